// Round 1
// baseline (46.751 us; speedup 1.0000x reference)
//
#include <hip/hip_runtime.h>

namespace {

constexpr int B = 16, H = 512, W = 512, N = 256;
constexpr int HWc = H * W;              // 262144
constexpr float LOG_CLAMP = -100.0f;

__device__ __forceinline__ float bce(float p, float t) {
    float logp   = fmaxf(logf(p), LOG_CLAMP);      // log(0) = -inf -> clamped to -100
    float log1mp = fmaxf(log1pf(-p), LOG_CLAMP);
    return -(t * logp + (1.0f - t) * log1mp);
}

__device__ __forceinline__ float smooth_l1(float pred, float tgt) {
    float d = fabsf(pred - tgt);
    return d < 1.0f ? 0.5f * d * d : d - 0.5f;
}

// Full-block sum; result valid on threadIdx.x == 0. Safe to call repeatedly.
__device__ __forceinline__ float block_reduce_sum(float v) {
    __shared__ float smem[8];                      // up to 512 threads / 64
    for (int off = 32; off > 0; off >>= 1)
        v += __shfl_down(v, off, 64);
    int lane = threadIdx.x & 63, wid = threadIdx.x >> 6;
    __syncthreads();                               // guard smem reuse across calls
    if (lane == 0) smem[wid] = v;
    __syncthreads();
    if (threadIdx.x == 0) {
        float s = 0.0f;
        int nw = (int)(blockDim.x >> 6);
        for (int i = 0; i < nw; ++i) s += smem[i];
        v = s;
    }
    return v;
}

// ---- Kernel 1: streaming BCE sum over text map (B*H*W = 4,194,304 elems) ----
__global__ void text_bce_kernel(const float4* __restrict__ p4,
                                const float4* __restrict__ t4,
                                float* __restrict__ ws) {
    const int n4 = B * HWc / 4;                    // 1,048,576 float4s
    int idx = blockIdx.x * blockDim.x + threadIdx.x;
    int stride = gridDim.x * blockDim.x;
    float acc = 0.0f;
    for (int i = idx; i < n4; i += stride) {
        float4 p = p4[i];
        float4 t = t4[i];
        acc += bce(p.x, t.x) + bce(p.y, t.y) + bce(p.z, t.z) + bce(p.w, t.w);
    }
    float s = block_reduce_sum(acc);
    if (threadIdx.x == 0) atomicAdd(&ws[0], s);
}

// ---- Kernel 2: per-box smooth-L1 + confidence BCE (one block per batch) ----
__global__ void box_kernel(const float* __restrict__ conf_pred,
                           const float* __restrict__ bbox_pred,
                           const float* __restrict__ box_conf,
                           const int*   __restrict__ box_xyxy,
                           const int*   __restrict__ box_mask,
                           float* __restrict__ ws) {
    int b = blockIdx.x;                            // batch
    int n = threadIdx.x;                           // box index (N == blockDim.x == 256)
    int bi = b * N + n;

    int4 xy = reinterpret_cast<const int4*>(box_xyxy)[bi];  // x1,y1,x2,y2 in [0, 512)
    int cx = (xy.x + xy.z) >> 1;                   // nonneg, so >>1 == floor div 2
    int cy = (xy.y + xy.w) >> 1;
    bool valid = (box_mask[bi] != 0) && cx >= 0 && cx < W && cy >= 0 && cy < H;
    int cxc = min(max(cx, 0), W - 1);
    int cyc = min(max(cy, 0), H - 1);

    int base = ((b * 4) * H + cyc) * W + cxc;      // bbox_pred[b, 0, cy, cx]
    // target = x/512.0f; 1/512 is a power of two so mul is exact
    float l1 = 0.25f * (smooth_l1(bbox_pred[base          ], (float)xy.x * (1.0f / W)) +
                        smooth_l1(bbox_pred[base +     HWc], (float)xy.y * (1.0f / H)) +
                        smooth_l1(bbox_pred[base + 2 * HWc], (float)xy.z * (1.0f / W)) +
                        smooth_l1(bbox_pred[base + 3 * HWc], (float)xy.w * (1.0f / H)));
    float cl = bce(conf_pred[(b * H + cyc) * W + cxc], box_conf[bi]);

    float vf = valid ? 1.0f : 0.0f;
    float s1 = block_reduce_sum(l1 * vf);
    float s2 = block_reduce_sum(cl * vf);
    float s3 = block_reduce_sum(vf);
    if (threadIdx.x == 0) {
        atomicAdd(&ws[1], s1);
        atomicAdd(&ws[2], s2);
        atomicAdd(&ws[3], s3);
    }
}

// ---- Kernel 3: combine ----
__global__ void finalize_kernel(const float* __restrict__ ws, float* __restrict__ out) {
    if (blockIdx.x == 0 && threadIdx.x == 0) {
        float text = ws[0] * (1.0f / (float)(B * HWc));   // exact pow2 divide
        float tb = ws[3];
        float denom = fmaxf(tb, 1.0f);
        bool any = tb > 0.0f;
        float box  = any ? ws[1] / denom : 0.0f;
        float conf = any ? ws[2] / denom : 0.0f;
        out[0] = text + box + conf;   // TEXT_MAP_W = BOX_W = CONF_W = 1
        out[1] = text;
        out[2] = box;
        out[3] = conf;
    }
}

}  // namespace

extern "C" void kernel_launch(void* const* d_in, const int* in_sizes, int n_in,
                              void* d_out, int out_size, void* d_ws, size_t ws_size,
                              hipStream_t stream) {
    const float* text_pred = (const float*)d_in[0];   // (16,1,512,512) f32
    const float* text_tgt  = (const float*)d_in[1];   // (16,1,512,512) f32
    const float* conf_pred = (const float*)d_in[2];   // (16,1,512,512) f32
    const float* bbox_pred = (const float*)d_in[3];   // (16,4,512,512) f32
    const float* box_conf  = (const float*)d_in[4];   // (16,256) f32
    const int*   box_xyxy  = (const int*)d_in[5];     // (16,256,4) i32
    const int*   box_mask  = (const int*)d_in[6];     // (16,256) bool -> int32

    float* out = (float*)d_out;                       // 4 floats
    float* ws  = (float*)d_ws;                        // 4 float accumulators

    // Harness poisons ws once and never re-poisons: zero it every call.
    hipMemsetAsync(ws, 0, 4 * sizeof(float), stream);

    text_bce_kernel<<<2048, 256, 0, stream>>>(
        (const float4*)text_pred, (const float4*)text_tgt, ws);
    box_kernel<<<B, N, 0, stream>>>(conf_pred, bbox_pred, box_conf, box_xyxy, box_mask, ws);
    finalize_kernel<<<1, 64, 0, stream>>>(ws, out);
}

// Round 2
// 23.657 us; speedup vs baseline: 1.9762x; 1.9762x over previous
//
#include <hip/hip_runtime.h>

namespace {

constexpr int B = 16, H = 512, W = 512, N = 256;
constexpr int HWc = H * W;              // 262144
constexpr int NBLK = 2048;              // text-reduction blocks
constexpr int NTHR = 256;
constexpr float LOG_CLAMP = -100.0f;

// ws layout (floats): [0,2048) text partials | [2048,2064) l1 | [2064,2080) conf | [2080,2096) valid
constexpr int WS_L1 = NBLK, WS_CL = NBLK + 16, WS_VF = NBLK + 32;

__device__ __forceinline__ float bce(float p, float t) {
    float logp   = fmaxf(logf(p), LOG_CLAMP);      // log(0) = -inf -> clamped
    float log1mp = fmaxf(log1pf(-p), LOG_CLAMP);
    return -(t * logp + (1.0f - t) * log1mp);
}

__device__ __forceinline__ float smooth_l1(float pred, float tgt) {
    float d = fabsf(pred - tgt);
    return d < 1.0f ? 0.5f * d * d : d - 0.5f;
}

// Full-block (256-thread) sum; result valid on threadIdx.x == 0. Reusable.
__device__ __forceinline__ float block_reduce_sum(float v) {
    __shared__ float smem[4];
    for (int off = 32; off > 0; off >>= 1)
        v += __shfl_down(v, off, 64);
    int lane = threadIdx.x & 63, wid = threadIdx.x >> 6;
    __syncthreads();                               // guard smem reuse across calls
    if (lane == 0) smem[wid] = v;
    __syncthreads();
    if (threadIdx.x == 0) v = smem[0] + smem[1] + smem[2] + smem[3];
    return v;
}

// ---- Kernel 1: text-map BCE partials + (blocks 0..15) box losses ----
__global__ __launch_bounds__(NTHR) void main_kernel(
        const float4* __restrict__ p4,
        const float4* __restrict__ t4,
        const float*  __restrict__ conf_pred,
        const float*  __restrict__ bbox_pred,
        const float*  __restrict__ box_conf,
        const int*    __restrict__ box_xyxy,
        const int*    __restrict__ box_mask,
        float* __restrict__ ws) {
    const int n4 = B * HWc / 4;                    // 1,048,576 float4s
    int idx = blockIdx.x * NTHR + threadIdx.x;
    float acc = 0.0f;
    #pragma unroll 2
    for (int i = idx; i < n4; i += NBLK * NTHR) {  // 2 iterations/thread
        float4 p = p4[i];
        float4 t = t4[i];
        acc += bce(p.x, t.x) + bce(p.y, t.y) + bce(p.z, t.z) + bce(p.w, t.w);
    }
    float s = block_reduce_sum(acc);
    if (threadIdx.x == 0) ws[blockIdx.x] = s;      // every slot written every call

    // Blocks 0..15: one batch of 256 boxes each (thread n = box n).
    if (blockIdx.x < B) {
        int b = blockIdx.x, n = threadIdx.x;
        int bi = b * N + n;
        int4 xy = reinterpret_cast<const int4*>(box_xyxy)[bi];  // x1,y1,x2,y2 in [0,512)
        int cx = (xy.x + xy.z) >> 1;               // nonneg -> >>1 == floor div 2
        int cy = (xy.y + xy.w) >> 1;
        bool valid = (box_mask[bi] != 0) && cx >= 0 && cx < W && cy >= 0 && cy < H;
        int cxc = min(max(cx, 0), W - 1);
        int cyc = min(max(cy, 0), H - 1);

        int base = ((b * 4) * H + cyc) * W + cxc;  // bbox_pred[b, 0, cy, cx]
        // target = coord/512.0f; 1/512 exact
        float l1 = 0.25f * (smooth_l1(bbox_pred[base          ], (float)xy.x * (1.0f / W)) +
                            smooth_l1(bbox_pred[base +     HWc], (float)xy.y * (1.0f / H)) +
                            smooth_l1(bbox_pred[base + 2 * HWc], (float)xy.z * (1.0f / W)) +
                            smooth_l1(bbox_pred[base + 3 * HWc], (float)xy.w * (1.0f / H)));
        float cl = bce(conf_pred[(b * H + cyc) * W + cxc], box_conf[bi]);

        float vf = valid ? 1.0f : 0.0f;
        float s1 = block_reduce_sum(l1 * vf);
        float s2 = block_reduce_sum(cl * vf);
        float s3 = block_reduce_sum(vf);
        if (threadIdx.x == 0) {
            ws[WS_L1 + b] = s1;
            ws[WS_CL + b] = s2;
            ws[WS_VF + b] = s3;
        }
    }
}

// ---- Kernel 2: final reduce of 2048 text partials + 48 box partials ----
__global__ __launch_bounds__(NTHR) void finalize_kernel(
        const float* __restrict__ ws, float* __restrict__ out) {
    float s = 0.0f;
    #pragma unroll
    for (int i = threadIdx.x; i < NBLK; i += NTHR) s += ws[i];
    float text_sum = block_reduce_sum(s);

    float v1 = threadIdx.x < 16 ? ws[WS_L1 + threadIdx.x] : 0.0f;
    float v2 = threadIdx.x < 16 ? ws[WS_CL + threadIdx.x] : 0.0f;
    float v3 = threadIdx.x < 16 ? ws[WS_VF + threadIdx.x] : 0.0f;
    float s1 = block_reduce_sum(v1);
    float s2 = block_reduce_sum(v2);
    float s3 = block_reduce_sum(v3);

    if (threadIdx.x == 0) {
        float text = text_sum * (1.0f / (float)(B * HWc));   // exact pow2 divide
        float denom = fmaxf(s3, 1.0f);
        bool any = s3 > 0.0f;
        float box  = any ? s1 / denom : 0.0f;
        float conf = any ? s2 / denom : 0.0f;
        out[0] = text + box + conf;   // all weights 1.0
        out[1] = text;
        out[2] = box;
        out[3] = conf;
    }
}

}  // namespace

extern "C" void kernel_launch(void* const* d_in, const int* in_sizes, int n_in,
                              void* d_out, int out_size, void* d_ws, size_t ws_size,
                              hipStream_t stream) {
    const float* text_pred = (const float*)d_in[0];   // (16,1,512,512) f32
    const float* text_tgt  = (const float*)d_in[1];   // (16,1,512,512) f32
    const float* conf_pred = (const float*)d_in[2];   // (16,1,512,512) f32
    const float* bbox_pred = (const float*)d_in[3];   // (16,4,512,512) f32
    const float* box_conf  = (const float*)d_in[4];   // (16,256) f32
    const int*   box_xyxy  = (const int*)d_in[5];     // (16,256,4) i32
    const int*   box_mask  = (const int*)d_in[6];     // (16,256) bool->i32

    float* out = (float*)d_out;                       // 4 floats
    float* ws  = (float*)d_ws;                        // >= 2096 floats

    main_kernel<<<NBLK, NTHR, 0, stream>>>(
        (const float4*)text_pred, (const float4*)text_tgt,
        conf_pred, bbox_pred, box_conf, box_xyxy, box_mask, ws);
    finalize_kernel<<<1, NTHR, 0, stream>>>(ws, out);
}

// Round 3
// 15.545 us; speedup vs baseline: 3.0074x; 1.5218x over previous
//
#include <hip/hip_runtime.h>

namespace {

constexpr int B = 16, H = 512, W = 512, N = 256;
constexpr int HWc = H * W;              // 262144
constexpr int NBLK = 2048;              // text-reduction blocks
constexpr int NTHR = 256;
// log2-domain clamp: max(ln(p), -100) == ln2 * max(log2(p), -100/ln2)
constexpr float LOG2_CLAMP = -144.26950408889634f;
constexpr float LN2 = 0.69314718055994531f;

// ws layout (floats): [0,2048) text partials | [2048,2064) l1 | [2064,2080) conf | [2080,2096) valid
constexpr int WS_L1 = NBLK, WS_CL = NBLK + 16, WS_VF = NBLK + 32;

// BCE in log2 domain (== bce/ln2). Native v_log_f32; log2(0) = -inf -> clamped.
__device__ __forceinline__ float bce2(float p, float t) {
    float m1 = fmaxf(__log2f(p), LOG2_CLAMP);
    float m2 = fmaxf(__log2f(1.0f - p), LOG2_CLAMP);
    // -(t*m1 + (1-t)*m2) = fma(t, m2-m1, -m2)
    return fmaf(t, m2 - m1, -m2);
}

__device__ __forceinline__ float smooth_l1(float pred, float tgt) {
    float d = fabsf(pred - tgt);
    return d < 1.0f ? 0.5f * d * d : d - 0.5f;
}

// Full-block sum (any multiple-of-64 block up to 512); valid on thread 0. Reusable.
__device__ __forceinline__ float block_reduce_sum(float v) {
    __shared__ float smem[8];
    for (int off = 32; off > 0; off >>= 1)
        v += __shfl_down(v, off, 64);
    int lane = threadIdx.x & 63, wid = threadIdx.x >> 6;
    __syncthreads();                               // guard smem reuse across calls
    if (lane == 0) smem[wid] = v;
    __syncthreads();
    if (threadIdx.x == 0) {
        float s = 0.0f;
        int nw = (int)(blockDim.x >> 6);
        for (int i = 0; i < nw; ++i) s += smem[i];
        v = s;
    }
    return v;
}

// ---- Kernel 1: text-map BCE partials (log2 domain) + (blocks 0..15) box losses ----
__global__ __launch_bounds__(NTHR) void main_kernel(
        const float4* __restrict__ p4,
        const float4* __restrict__ t4,
        const float*  __restrict__ conf_pred,
        const float*  __restrict__ bbox_pred,
        const float*  __restrict__ box_conf,
        const int*    __restrict__ box_xyxy,
        const int*    __restrict__ box_mask,
        float* __restrict__ ws) {
    const int n4 = B * HWc / 4;                    // 1,048,576 float4s
    int idx = blockIdx.x * NTHR + threadIdx.x;
    float acc = 0.0f;
    #pragma unroll 2
    for (int i = idx; i < n4; i += NBLK * NTHR) {  // 2 iterations/thread
        float4 p = p4[i];
        float4 t = t4[i];
        acc += bce2(p.x, t.x) + bce2(p.y, t.y) + bce2(p.z, t.z) + bce2(p.w, t.w);
    }
    float s = block_reduce_sum(acc);
    if (threadIdx.x == 0) ws[blockIdx.x] = s;      // every slot written every call

    // Blocks 0..15: one batch of 256 boxes each (thread n = box n).
    if (blockIdx.x < B) {
        int b = blockIdx.x, n = threadIdx.x;
        int bi = b * N + n;
        int4 xy = reinterpret_cast<const int4*>(box_xyxy)[bi];  // x1,y1,x2,y2 in [0,512)
        int cx = (xy.x + xy.z) >> 1;               // nonneg -> >>1 == floor div 2
        int cy = (xy.y + xy.w) >> 1;
        bool valid = (box_mask[bi] != 0) && cx >= 0 && cx < W && cy >= 0 && cy < H;
        int cxc = min(max(cx, 0), W - 1);
        int cyc = min(max(cy, 0), H - 1);

        int base = ((b * 4) * H + cyc) * W + cxc;  // bbox_pred[b, 0, cy, cx]
        // target = coord/512.0f; 1/512 exact pow2
        float l1 = 0.25f * (smooth_l1(bbox_pred[base          ], (float)xy.x * (1.0f / W)) +
                            smooth_l1(bbox_pred[base +     HWc], (float)xy.y * (1.0f / H)) +
                            smooth_l1(bbox_pred[base + 2 * HWc], (float)xy.z * (1.0f / W)) +
                            smooth_l1(bbox_pred[base + 3 * HWc], (float)xy.w * (1.0f / H)));
        float cl = bce2(conf_pred[(b * H + cyc) * W + cxc], box_conf[bi]);  // log2 domain

        float vf = valid ? 1.0f : 0.0f;
        float s1 = block_reduce_sum(l1 * vf);
        float s2 = block_reduce_sum(cl * vf);
        float s3 = block_reduce_sum(vf);
        if (threadIdx.x == 0) {
            ws[WS_L1 + b] = s1;
            ws[WS_CL + b] = s2;   // log2 domain, scaled by ln2 in finalize
            ws[WS_VF + b] = s3;
        }
    }
}

// ---- Kernel 2: final reduce of 2048 text partials + 48 box partials ----
__global__ __launch_bounds__(512) void finalize_kernel(
        const float* __restrict__ ws, float* __restrict__ out) {
    float s = 0.0f;
    #pragma unroll
    for (int i = threadIdx.x; i < NBLK; i += 512) s += ws[i];   // 4 loads/thread
    float text_sum = block_reduce_sum(s);

    float v1 = threadIdx.x < 16 ? ws[WS_L1 + threadIdx.x] : 0.0f;
    float v2 = threadIdx.x < 16 ? ws[WS_CL + threadIdx.x] : 0.0f;
    float v3 = threadIdx.x < 16 ? ws[WS_VF + threadIdx.x] : 0.0f;
    float s1 = block_reduce_sum(v1);
    float s2 = block_reduce_sum(v2);
    float s3 = block_reduce_sum(v3);

    if (threadIdx.x == 0) {
        float text = text_sum * (LN2 / (float)(B * HWc));   // back to ln domain + mean
        float denom = fmaxf(s3, 1.0f);
        bool any = s3 > 0.0f;
        float box  = any ? s1 / denom : 0.0f;
        float conf = any ? (s2 * LN2) / denom : 0.0f;
        out[0] = text + box + conf;   // all weights 1.0
        out[1] = text;
        out[2] = box;
        out[3] = conf;
    }
}

}  // namespace

extern "C" void kernel_launch(void* const* d_in, const int* in_sizes, int n_in,
                              void* d_out, int out_size, void* d_ws, size_t ws_size,
                              hipStream_t stream) {
    const float* text_pred = (const float*)d_in[0];   // (16,1,512,512) f32
    const float* text_tgt  = (const float*)d_in[1];   // (16,1,512,512) f32
    const float* conf_pred = (const float*)d_in[2];   // (16,1,512,512) f32
    const float* bbox_pred = (const float*)d_in[3];   // (16,4,512,512) f32
    const float* box_conf  = (const float*)d_in[4];   // (16,256) f32
    const int*   box_xyxy  = (const int*)d_in[5];     // (16,256,4) i32
    const int*   box_mask  = (const int*)d_in[6];     // (16,256) bool->i32

    float* out = (float*)d_out;                       // 4 floats
    float* ws  = (float*)d_ws;                        // >= 2096 floats

    main_kernel<<<NBLK, NTHR, 0, stream>>>(
        (const float4*)text_pred, (const float4*)text_tgt,
        conf_pred, bbox_pred, box_conf, box_xyxy, box_mask, ws);
    finalize_kernel<<<1, 512, 0, stream>>>(ws, out);
}